// Round 13
// baseline (134.248 us; speedup 1.0000x reference)
//
#include <hip/hip_runtime.h>

#define BB 32
#define OO 64
#define II 64
#define FF 16
#define HH 128
#define WW 128

typedef __attribute__((ext_vector_type(8))) __bf16 bf16x8;
typedef __attribute__((ext_vector_type(4))) float f32x4;
typedef __attribute__((ext_vector_type(16))) float f32x16;

typedef __attribute__((address_space(3))) uint8_t  lds_u8;
typedef __attribute__((address_space(1))) const uint8_t g_u8;

// ---------------- Kernel 1: weight/bias generation ----------------
__global__ __launch_bounds__(64)
void gen_weights(const float* __restrict__ addr,
                 const float* __restrict__ w_bank,
                 const float* __restrict__ b_bank,
                 __bf16* __restrict__ wT,
                 float* __restrict__ bias_out) {
    const int bo  = blockIdx.x;            // b*64 + o
    const int tid = threadIdx.x;           // i = 0..63

    __shared__ float bank_s[FF * 9];
    __shared__ float bbank_s[FF];
    for (int idx = tid; idx < FF * 9; idx += 64) bank_s[idx] = w_bank[idx];
    if (tid < FF) bbank_s[tid] = b_bank[tid];
    __syncthreads();

    const float* arow = addr + ((size_t)bo * (II + 1) + 1 + tid) * FF;
    float a[FF];
    float m = -1e30f;
#pragma unroll
    for (int f = 0; f < FF; ++f) { a[f] = arow[f]; m = fmaxf(m, a[f]); }
    float s = 0.f;
#pragma unroll
    for (int f = 0; f < FF; ++f) { a[f] = __expf(a[f] - m); s += a[f]; }
    const float inv = 1.0f / s;

    const int b = bo >> 6, o = bo & 63;
#pragma unroll
    for (int kl = 0; kl < 9; ++kl) {
        float acc = 0.f;
#pragma unroll
        for (int f = 0; f < FF; ++f) acc += a[f] * bank_s[f * 9 + kl];
        wT[(((size_t)b * 9 + kl) * OO + o) * II + tid] = (__bf16)(acc * inv);
    }

    if (tid == 0) {
        const float* brow = addr + (size_t)bo * (II + 1) * FF;
        float bb[FF];
        float bm = -1e30f;
#pragma unroll
        for (int f = 0; f < FF; ++f) { bb[f] = brow[f]; bm = fmaxf(bm, bb[f]); }
        float bs = 0.f;
#pragma unroll
        for (int f = 0; f < FF; ++f) { bb[f] = __expf(bb[f] - bm); bs += bb[f]; }
        float acc = 0.f;
#pragma unroll
        for (int f = 0; f < FF; ++f) acc += bb[f] * bbank_s[f];
        bias_out[bo] = acc / bs;
    }
}

// ---------------- Kernel 2: fused transpose + implicit-GEMM conv ----------------
// 512 threads (8 waves), 1 block/CU, grid 256. Block: (b, px-half, 32-row
// group); 8 phases of {4 rows x 64 px x 64 o}. Wave = (row r, px-32 q):
// 64 o x 32 px via mfma_f32_32x32x16_bf16 (2 o-tiles share each B-read ->
// 3 LDS reads per 2 MFMAs; 25% less LDS-read traffic than the 16x16 form,
// half the MFMA instruction count). A (72KB) + 10-slot x ring (84.5KB) +
// bias table (256B) in LDS. Staging: issue-A / 18ks / issue-B + write-A /
// 18ks / write-B (>=18ks of latency cover before any vmcnt wait).
#define SLOTB 8448               // 66 px * 128 B
#define NSLOT 10
#define RING  73728              // A region = [0, 73728)
#define BIASOFF (RING + NSLOT * SLOTB)   // 158208
#define LDSZ (BIASOFF + 256)             // 158464 B

// load global x rows (R0+pr-1, R0+pr) [padded rows pr, pr+1] into s0_,s1_,st_
#define LOADPAIR(pr_, s0_, s1_, st_) do {                                          \
    const int pxg_ = ph * 64 + l - 1;                                              \
    const bool okpx_ = (unsigned)pxg_ < 128u;                                      \
    _Pragma("unroll")                                                              \
    for (int j_ = 0; j_ < 2; ++j_) {                                               \
        const int gr_ = R0 + (pr_) + j_ - 1;                                       \
        const bool ok_ = okpx_ && ((unsigned)gr_ < 128u);                          \
        const float* xs_ = xb + ((size_t)(wv * 8) * HH + gr_) * WW + pxg_;         \
        float* dst_ = j_ ? (s1_) : (s0_);                                          \
        _Pragma("unroll")                                                          \
        for (int jj_ = 0; jj_ < 8; ++jj_) {                                        \
            float v_ = 0.f;                                                        \
            if (ok_) v_ = xs_[(size_t)jj_ * (HH * WW)];                            \
            dst_[jj_] = v_;                                                        \
        }                                                                          \
    }                                                                              \
    {   /* tail: local px 64,65 for both rows; lanes 0..31 of wave 0 */            \
        const int lr_ = l >> 4;                                                    \
        const int cc_ = (l >> 1) & 7;                                              \
        const int pxl_ = 64 + (l & 1);                                             \
        const int pxg2_ = ph * 64 + pxl_ - 1;                                      \
        const int gr_ = R0 + (pr_) + lr_ - 1;                                      \
        const bool ok_ = (t < 32) && ((unsigned)pxg2_ < 128u)                      \
                         && ((unsigned)gr_ < 128u);                                \
        const float* xs_ = xb + ((size_t)(cc_ * 8) * HH + gr_) * WW + pxg2_;       \
        _Pragma("unroll")                                                          \
        for (int jj_ = 0; jj_ < 8; ++jj_) {                                        \
            float v_ = 0.f;                                                        \
            if (ok_) v_ = xs_[(size_t)jj_ * (HH * WW)];                            \
            (st_)[jj_] = v_;                                                       \
        }                                                                          \
    }                                                                              \
} while (0)

// convert + swizzled ds_write of the pair into ring slots sA_, sB_
#define WRITEPAIR(sA_, sB_, s0_, s1_, st_) do {                                    \
    bf16x8 u_;                                                                     \
    _Pragma("unroll")                                                              \
    for (int jj_ = 0; jj_ < 8; ++jj_) u_[jj_] = (__bf16)(s0_)[jj_];                \
    *(bf16x8*)(LDS + RING + (sA_) * SLOTB + l * 128                                \
               + ((wv ^ (l & 7)) << 4)) = u_;                                      \
    _Pragma("unroll")                                                              \
    for (int jj_ = 0; jj_ < 8; ++jj_) u_[jj_] = (__bf16)(s1_)[jj_];                \
    *(bf16x8*)(LDS + RING + (sB_) * SLOTB + l * 128                                \
               + ((wv ^ (l & 7)) << 4)) = u_;                                      \
    if (t < 32) {                                                                  \
        const int lr_ = l >> 4;                                                    \
        const int cc_ = (l >> 1) & 7;                                              \
        const int pxl_ = 64 + (l & 1);                                             \
        const int sl_ = lr_ ? (sB_) : (sA_);                                       \
        _Pragma("unroll")                                                          \
        for (int jj_ = 0; jj_ < 8; ++jj_) u_[jj_] = (__bf16)(st_)[jj_];            \
        *(bf16x8*)(LDS + RING + sl_ * SLOTB + pxl_ * 128                           \
                   + ((cc_ ^ (pxl_ & 7)) << 4)) = u_;                              \
    }                                                                              \
} while (0)

// k-steps [K0_, K1_): ks = kl*4 + s; per ks: 2 A-reads + 1 B-read + 2 MFMA
#define KS_RANGE(K0_, K1_) do {                                                    \
    _Pragma("unroll")                                                              \
    for (int ks = (K0_); ks < (K1_); ++ks) {                                       \
        const int kl = ks >> 2, s = ks & 3;                                        \
        const int dr = kl / 3, dc = kl - 3 * dr;                                   \
        const int ck = 2 * s + lhi;          /* logical k-chunk 0..7 */            \
        const bf16x8 af0 = *(const bf16x8*)(LDS + kl * 8192 + l31 * 128            \
                              + ((ck ^ l7) << 4));                                 \
        const bf16x8 af1 = *(const bf16x8*)(LDS + kl * 8192 + (32 + l31) * 128     \
                              + ((ck ^ l7) << 4));                                 \
        const int pxl = q * 32 + l31 + dc;                                         \
        const bf16x8 bv = *(const bf16x8*)(LDS + o3[dr] + pxl * 128                \
                              + ((ck ^ (pxl & 7)) << 4));                          \
        acc0 = __builtin_amdgcn_mfma_f32_32x32x16_bf16(af0, bv, acc0, 0, 0, 0);    \
        acc1 = __builtin_amdgcn_mfma_f32_32x32x16_bf16(af1, bv, acc1, 0, 0, 0);    \
    }                                                                              \
} while (0)

__global__ __launch_bounds__(512, 1)
void conv_fused(const float* __restrict__ x, const __bf16* __restrict__ wT,
                const float* __restrict__ bias, float* __restrict__ y) {
    __shared__ __align__(16) char LDS[LDSZ];

    // bijective XCD swizzle: blocks of one batch share an XCD
    const int hwid = blockIdx.x;
    const int work = (hwid & 7) * 32 + (hwid >> 3);
    const int b  = work >> 3;
    const int r3 = work & 7;
    const int ph = r3 >> 2;                // px half (64 px)
    const int rg = r3 & 3;                 // 32-row group
    const int R0 = rg * 32;

    const int t  = threadIdx.x;
    const int wv = t >> 6;                 // wave 0..7
    const int l  = t & 63;
    const int r  = wv >> 1;                // wave's row within phase (0..3)
    const int q  = wv & 1;                 // px 32-group
    const int l31 = l & 31, lhi = l >> 5, l7 = l & 7;

    const __bf16* wb = wT + (size_t)b * 9 * OO * II;
    const float*  xb = x + (size_t)b * II * HH * WW;

    // ---- prologue: stage A (4608 chunks, source-swizzled) ----
#pragma unroll
    for (int it = 0; it < 9; ++it) {
        const int cid = it * 512 + t;
        const int kl  = cid >> 9;
        const int rem = cid & 511;
        const int o   = rem >> 3;
        const int c   = rem & 7;
        const __bf16* src = wb + ((kl * 64 + o) << 6) + ((c ^ (o & 7)) << 3);
        __builtin_amdgcn_global_load_lds((g_u8*)src,
            (lds_u8*)(LDS + (size_t)(it * 512 + (t & 448)) * 16), 16, 0, 0);
    }
    // bias -> LDS table
    if (t < 64) *(float*)(LDS + BIASOFF + t * 4) = bias[b * OO + t];

    float smA0[8], smA1[8], smAt[8];

    // stage x padded rows 0..5 into slots 0..5
    LOADPAIR(0, smA0, smA1, smAt); WRITEPAIR(0, 1, smA0, smA1, smAt);
    LOADPAIR(2, smA0, smA1, smAt); WRITEPAIR(2, 3, smA0, smA1, smAt);
    LOADPAIR(4, smA0, smA1, smAt); WRITEPAIR(4, 5, smA0, smA1, smAt);

    f32x16 acc0 = {}, acc1 = {};

    __syncthreads();                       // A + bias + rows 0..5 landed

    int s0 = 0;                            // slot of padded row 4p
    for (int p = 0; p < 8; ++p) {
        // wave's 3 read-slot byte offsets (runtime values, STATIC dr index)
        int d0_ = s0 + r;  if (d0_ >= NSLOT) d0_ -= NSLOT;
        int d1_ = d0_ + 1; if (d1_ >= NSLOT) d1_ -= NSLOT;
        int d2_ = d1_ + 1; if (d2_ >= NSLOT) d2_ -= NSLOT;
        const int o3[3] = { RING + d0_ * SLOTB, RING + d1_ * SLOTB,
                            RING + d2_ * SLOTB };
        int wA = s0 + 6; if (wA >= NSLOT) wA -= NSLOT;
        int wB = wA + 1; if (wB >= NSLOT) wB -= NSLOT;
        int wC = wB + 1; if (wC >= NSLOT) wC -= NSLOT;
        int wD = wC + 1; if (wD >= NSLOT) wD -= NSLOT;
        const int pr = 4 * p;
        const bool pf = (p < 7);

        float smB0[8], smB1[8], smBt[8];

        if (pf) LOADPAIR(pr + 6, smA0, smA1, smAt);   // issue pair A
        KS_RANGE(0, 18);                              // 18 ks of cover
        if (pf) {
            LOADPAIR(pr + 8, smB0, smB1, smBt);       // issue pair B first,
            WRITEPAIR(wA, wB, smA0, smA1, smAt);      // then land pair A
        }
        KS_RANGE(18, 36);
        if (pf) WRITEPAIR(wC, wD, smB0, smB1, smBt);  // land pair B

        __syncthreads();                   // ring rotated; next rows visible

        // epilogue: bias-add + store, acc reset
        const int row = R0 + pr + r;
        const int col = ph * 64 + q * 32 + l31;
#pragma unroll
        for (int mo = 0; mo < 2; ++mo) {
#pragma unroll
            for (int g = 0; g < 4; ++g) {
                const f32x4 bb = *(const f32x4*)(LDS + BIASOFF
                                   + (mo * 32 + 8 * g + 4 * lhi) * 4);
#pragma unroll
                for (int j = 0; j < 4; ++j) {
                    const int o = mo * 32 + 8 * g + 4 * lhi + j;
                    const float v = (mo ? acc1[4 * g + j] : acc0[4 * g + j])
                                    + bb[j];
                    y[(((size_t)b * OO + o) * HH + row) * WW + col] = v;
                }
            }
        }
        acc0 = f32x16{};
        acc1 = f32x16{};

        s0 += 4; if (s0 >= NSLOT) s0 -= NSLOT;
    }
}

extern "C" void kernel_launch(void* const* d_in, const int* in_sizes, int n_in,
                              void* d_out, int out_size, void* d_ws, size_t ws_size,
                              hipStream_t stream) {
    const float* addresses = (const float*)d_in[0];   // (B,O,I+1,F)
    const float* x         = (const float*)d_in[1];   // (B,I,H,W)
    const float* w_bank    = (const float*)d_in[2];   // (F,3,3)
    const float* b_bank    = (const float*)d_in[3];   // (F,)
    float* out = (float*)d_out;                       // (B,O,H,W)

    // ws layout: [bias 8KB][wT 2.25MB]
    float*  bias_ws = (float*)d_ws;
    __bf16* wT      = (__bf16*)((char*)d_ws + 8192);

    gen_weights<<<BB * OO, 64, 0, stream>>>(addresses, w_bank, b_bank, wT, bias_ws);
    conv_fused<<<256, 512, 0, stream>>>(x, wT, bias_ws, out);
}